// Round 1
// baseline (257.001 us; speedup 1.0000x reference)
//
#include <hip/hip_runtime.h>
#include <math.h>

typedef _Float16 f16;
typedef _Float16 f16x4 __attribute__((ext_vector_type(4)));
typedef _Float16 f16x8 __attribute__((ext_vector_type(8)));
typedef float f32x4 __attribute__((ext_vector_type(4)));

#define AS1 __attribute__((address_space(1)))
#define AS3 __attribute__((address_space(3)))

__device__ __forceinline__ void gload_lds16(const void* g, void* l) {
    __builtin_amdgcn_global_load_lds((AS1 void*)(g), (AS3 void*)(l), 16, 0, 0);
}

// ---------------- weight transpose + cast: Wt[n][k] = (f16) W[k][n] ----------------
__global__ void wt_kernel(const float* __restrict__ W, f16* __restrict__ Wt, int K, int N) {
    int k = blockIdx.x * 64 + (threadIdx.x & 63);
    int n = blockIdx.y * 4 + (threadIdx.x >> 6);
    Wt[(size_t)n * K + k] = (f16)W[(size_t)k * N + n];
}

// ---------------- embedding cast to f16, padded rows zeroed ----------------
__global__ void ecast_kernel(const float* __restrict__ emb, f16* __restrict__ E) {
    int r = blockIdx.x;
    int tid = threadIdx.x; // 64 threads, 4 floats each
    float4 v = make_float4(0.f, 0.f, 0.f, 0.f);
    if (r < 10000) v = *(const float4*)&emb[(size_t)r * 256 + tid * 4];
    f16x4 h;
    h[0] = (f16)v.x; h[1] = (f16)v.y; h[2] = (f16)v.z; h[3] = (f16)v.w;
    *(f16x4*)&E[(size_t)r * 256 + tid * 4] = h;
}

// ---------------- GEMM: C = act(A @ Bt^T + bias) ----------------
// A [Mrows, K] f16 row-major; Bt [N, K] f16 row-major; C [Mrows, N] f16
enum { ACT_RELU_B = 0, ACT_TANH_B = 1, ACT_SIG_B = 2, ACT_TANH_B_MUL = 3, ACT_RELU_NOB = 4 };

template <int ACT>
__global__ void gemm_act(const f16* __restrict__ A, const f16* __restrict__ Bt,
                         const float* __restrict__ bias, f16* __restrict__ C,
                         int N, int K) {
    __shared__ f16 As[128 * 64];
    __shared__ f16 Bs[128 * 64];
    const int tid = threadIdx.x;
    const int wave = tid >> 6, lane = tid & 63;
    const int wr = wave >> 1, wc = wave & 1;
    const int row0 = blockIdx.x * 128, col0 = blockIdx.y * 128;
    const int lo16 = lane & 15, hi4 = lane >> 4;

    f32x4 acc[4][4] = {};

    for (int k0 = 0; k0 < K; k0 += 64) {
#pragma unroll
        for (int it = 0; it < 4; ++it) {
            int c = it * 256 + wave * 64 + lane;   // 16B chunk id, lane-contiguous per wave
            int r = c >> 3, kcol = (c & 7) * 8;
            gload_lds16(A  + (size_t)(row0 + r) * K + (k0 + kcol), &As[c * 8]);
            gload_lds16(Bt + (size_t)(col0 + r) * K + (k0 + kcol), &Bs[c * 8]);
        }
        __syncthreads();
#pragma unroll
        for (int kk = 0; kk < 64; kk += 32) {
            f16x8 af[4], bf[4];
#pragma unroll
            for (int m = 0; m < 4; ++m)
                af[m] = *(const f16x8*)&As[(wr * 64 + m * 16 + lo16) * 64 + kk + hi4 * 8];
#pragma unroll
            for (int n = 0; n < 4; ++n)
                bf[n] = *(const f16x8*)&Bs[(wc * 64 + n * 16 + lo16) * 64 + kk + hi4 * 8];
#pragma unroll
            for (int m = 0; m < 4; ++m)
#pragma unroll
                for (int n = 0; n < 4; ++n)
                    acc[m][n] = __builtin_amdgcn_mfma_f32_16x16x32_f16(af[m], bf[n], acc[m][n], 0, 0, 0);
        }
        __syncthreads();
    }

    // epilogue: D mapping col=lane&15, row=(lane>>4)*4+j
    const int rl = hi4 * 4;
#pragma unroll
    for (int n = 0; n < 4; ++n) {
        int col = col0 + wc * 64 + n * 16 + lo16;
        float b = 0.f;
        if (ACT != ACT_RELU_NOB) b = bias[col];
#pragma unroll
        for (int m = 0; m < 4; ++m) {
#pragma unroll
            for (int j = 0; j < 4; ++j) {
                int row = row0 + wr * 64 + m * 16 + rl + j;
                size_t idx = (size_t)row * N + col;
                float v = acc[m][n][j] + b;
                float o;
                if (ACT == ACT_RELU_B || ACT == ACT_RELU_NOB) o = fmaxf(v, 0.f);
                else if (ACT == ACT_TANH_B) o = tanhf(v);
                else if (ACT == ACT_SIG_B) o = 1.f / (1.f + expf(-v));
                else o = tanhf(v) * (float)C[idx];   // ACT_TANH_B_MUL: C holds I (sigmoid) values
                C[idx] = (f16)o;
            }
        }
    }
}

// ---------------- scan over T + fused output projection ----------------
// s_{t+1} = relu(u_v + relu(m_v * s_t + p_v)),  v = tokens[b][t]; out = sigmoid(s@Wout+bout)
__global__ __launch_bounds__(256) void scan_out_kernel(
    const int* __restrict__ tokens, const f16* __restrict__ Mt, const f16* __restrict__ Pt,
    const f16* __restrict__ Ut, const float* __restrict__ state0,
    const float* __restrict__ Wout, const float* __restrict__ bout, float* __restrict__ out) {
    __shared__ int toks[256];
    __shared__ float red[256];
    const int b = blockIdx.x, tid = threadIdx.x;
    if (tid < 250) toks[tid] = tokens[b * 250 + tid];
    __syncthreads();

    float4 sv = *(const float4*)&state0[(size_t)b * 1024 + tid * 4];
    float s[4] = {sv.x, sv.y, sv.z, sv.w};

    for (int t = 0; t < 250; ++t) {
        size_t base = (size_t)toks[t] * 1024 + tid * 4;
        f16x4 m = *(const f16x4*)&Mt[base];
        f16x4 p = *(const f16x4*)&Pt[base];
        f16x4 u = *(const f16x4*)&Ut[base];
#pragma unroll
        for (int j = 0; j < 4; ++j) {
            float y = fmaxf((float)m[j] * s[j] + (float)p[j], 0.f);
            s[j] = fmaxf((float)u[j] + y, 0.f);
        }
    }

    float part = 0.f;
#pragma unroll
    for (int j = 0; j < 4; ++j) part += s[j] * Wout[tid * 4 + j];
    red[tid] = part;
    __syncthreads();
    for (int off = 128; off > 0; off >>= 1) {
        if (tid < off) red[tid] += red[tid + off];
        __syncthreads();
    }
    if (tid == 0) out[b] = 1.f / (1.f + expf(-(red[0] + bout[0])));
}

extern "C" void kernel_launch(void* const* d_in, const int* in_sizes, int n_in,
                              void* d_out, int out_size, void* d_ws, size_t ws_size,
                              hipStream_t stream) {
    const int*   tokens = (const int*)  d_in[0];
    const float* emb    = (const float*)d_in[1];
    const float* W1     = (const float*)d_in[2];
    const float* b1     = (const float*)d_in[3];
    const float* W2     = (const float*)d_in[4];
    const float* b2     = (const float*)d_in[5];
    const float* W3     = (const float*)d_in[6];
    const float* b3     = (const float*)d_in[7];
    const float* W4     = (const float*)d_in[8];
    const float* b4     = (const float*)d_in[9];
    const float* W5     = (const float*)d_in[10];
    const float* Wout   = (const float*)d_in[11];
    const float* bout   = (const float*)d_in[12];
    const float* state0 = (const float*)d_in[13];
    float* out = (float*)d_out;

    const int RP = 10112;  // 79 * 128, padded vocab rows

    char* ws = (char*)d_ws;
    size_t off = 0;
    auto alloc = [&](size_t bytes) -> void* {
        void* p = ws + off;
        off += (bytes + 255) & ~(size_t)255;
        return p;
    };
    f16* Wt1 = (f16*)alloc((size_t)2048 * 256 * 2);
    f16* Wt2 = (f16*)alloc((size_t)1024 * 2048 * 2);
    f16* Wt3 = (f16*)alloc((size_t)1024 * 256 * 2);
    f16* Wt4 = (f16*)alloc((size_t)1024 * 256 * 2);
    f16* Wt5 = (f16*)alloc((size_t)1024 * 256 * 2);
    f16* E   = (f16*)alloc((size_t)RP * 256 * 2);
    f16* Rb  = (f16*)alloc((size_t)RP * 2048 * 2);
    f16* Mt  = (f16*)alloc((size_t)RP * 1024 * 2);
    f16* Pt  = (f16*)alloc((size_t)RP * 1024 * 2);
    f16* Ut  = (f16*)alloc((size_t)RP * 1024 * 2);
    (void)ws_size; (void)in_sizes; (void)n_in; (void)out_size;

    // weights -> f16 transposed [N][K]
    wt_kernel<<<dim3(256 / 64, 2048 / 4), 256, 0, stream>>>(W1, Wt1, 256, 2048);
    wt_kernel<<<dim3(2048 / 64, 1024 / 4), 256, 0, stream>>>(W2, Wt2, 2048, 1024);
    wt_kernel<<<dim3(256 / 64, 1024 / 4), 256, 0, stream>>>(W3, Wt3, 256, 1024);
    wt_kernel<<<dim3(256 / 64, 1024 / 4), 256, 0, stream>>>(W4, Wt4, 256, 1024);
    wt_kernel<<<dim3(256 / 64, 1024 / 4), 256, 0, stream>>>(W5, Wt5, 256, 1024);
    ecast_kernel<<<RP, 64, 0, stream>>>(emb, E);

    // per-vocab tables
    gemm_act<ACT_RELU_B>    <<<dim3(RP / 128, 2048 / 128), 256, 0, stream>>>(E,  Wt1, b1, Rb, 2048, 256);
    gemm_act<ACT_TANH_B>    <<<dim3(RP / 128, 1024 / 128), 256, 0, stream>>>(Rb, Wt2, b2, Mt, 1024, 2048);
    gemm_act<ACT_SIG_B>     <<<dim3(RP / 128, 1024 / 128), 256, 0, stream>>>(E,  Wt3, b3, Pt, 1024, 256);
    gemm_act<ACT_TANH_B_MUL><<<dim3(RP / 128, 1024 / 128), 256, 0, stream>>>(E,  Wt4, b4, Pt, 1024, 256);
    gemm_act<ACT_RELU_NOB>  <<<dim3(RP / 128, 1024 / 128), 256, 0, stream>>>(E,  Wt5, nullptr, Ut, 1024, 256);

    // scan + output projection
    scan_out_kernel<<<256, 256, 0, stream>>>(tokens, Mt, Pt, Ut, state0, Wout, bout, out);
}